// Round 1
// 70.058 us; speedup vs baseline: 1.0230x; 1.0230x over previous
//
#include <hip/hip_runtime.h>

#define ML 16
#define NW 1000
#define NBS 64

// Fused kernel: each block rebuilds the global char->row bitmask from x
// (4 KB, L2-resident) in LDS, then runs the register-resident DP.
//
// charmask cm[c]: bit i (i=1..16) set iff any of the 64 sequences has char c
// at x-position (i-2) & 15  (row i uses x[:,:,i-2]; Python negative-index
// wrap: i=1 -> pos 15). NOTE: the reference's DA table is GLOBAL across all
// (b,s) sequences (da has no batch dim and is scatter-set with xi over all
// sequences), so a global charmask is semantically correct.
//
// Per-lane DP state (one lane per (b,s,word)):
//  - prev[16]: previous DP row
//  - mk[t]   : maxdist - k_t  (k_t = DA[i][wc[t]]; k=0 -> mk=maxdist)
//  - tb[t]   : DP(k, t+1) - k at last row k where wc[t] appeared
//              (k=0 -> tb=maxdist, folds the border case)
// Transposition term per cell (i,j), t=j-2:
//   l==0          -> trans = mk[t] + (i + j - 1)
//   l=j-1, k==i   -> trans = left   (previous cell in current row)
//   l=j-1, k<i    -> trans = tb[t] + i
//
// v2 changes vs the 71.2 µs kernel:
//  - i-loop FULLY unrolled: no runtime-indexed register arrays (xc[] was
//    going to scratch — rule: runtime-indexed ext arrays -> local memory),
//    and fi / (i+j-1) / bit-index i all fold to compile-time literals.
//  - per-row p1[j] = prev[j]+1 shared between the "up+1" of cell j and the
//    "diag+1" of cell j+1 (saves one add per cell).
//  - cost folded into one cndmask: dce = eq ? diag : diag+1.
//  - min tree written left-deep so clang fuses to v_min3_f32 + v_min.
//  - result capture is a scalar branch: sq1 is block-uniform ->
//    readfirstlane + (su == j) compile-time-j comparison (s_cmp/s_cbranch),
//    only one j per row pays the per-lane (i == rowcap) cndmask.
__global__ __launch_bounds__(256) void dl_fused_kernel(
    const int* __restrict__ x,
    const int* __restrict__ words,
    const int* __restrict__ word_lengths,
    const float* __restrict__ out_scale,
    float* __restrict__ out)
{
    __shared__ unsigned cm[32];
    const int tid = threadIdx.x;
    const int lane = tid & 63;
    const int wv = tid >> 6;                     // 0..3
    const int bs = blockIdx.x >> 2;              // 0..63
    const int chunk = (blockIdx.x & 3) * 4 + wv; // 0..15
    const int w_raw = chunk * 64 + lane;
    const bool active = (w_raw < NW);
    const int w = active ? w_raw : (NW - 1);
    const float s = out_scale[0];

    // ---- build charmask in LDS (wave 0 lanes cooperate; 64 seqs) ----
    if (tid < 32) cm[tid] = 0u;
    __syncthreads();
    if (tid < 64) {
        const int* xq = x + tid * ML;
        #pragma unroll
        for (int p = 0; p < ML; ++p) {
            int c = xq[p];                       // 0..27
            int i = (p <= 14) ? (p + 2) : 1;
            atomicOr(&cm[c], 1u << i);
        }
    }
    __syncthreads();

    // ---- wave-uniform x row: argmin (first min) = seq_wl ----
    const int* xr = x + bs * ML;
    int xc[ML];
    #pragma unroll
    for (int p = 0; p < ML; ++p) xc[p] = xr[p];
    int minv = xc[0], seq_wl = 0;
    #pragma unroll
    for (int p = 1; p < ML; ++p)
        if (xc[p] < minv) { minv = xc[p]; seq_wl = p; }
    // block-uniform capture column (1..16) -> scalar register
    const int su = __builtin_amdgcn_readfirstlane(seq_wl + 1);

    // ---- per-lane word chars (coalesced 16B loads) + row bitmasks ----
    int wc[ML];
    const int4* wp = (const int4*)(words + w * ML);
    int4 q0 = wp[0], q1 = wp[1], q2 = wp[2], q3 = wp[3];
    wc[0]=q0.x; wc[1]=q0.y; wc[2]=q0.z; wc[3]=q0.w;
    wc[4]=q1.x; wc[5]=q1.y; wc[6]=q1.z; wc[7]=q1.w;
    wc[8]=q2.x; wc[9]=q2.y; wc[10]=q2.z; wc[11]=q2.w;
    wc[12]=q3.x; wc[13]=q3.y; wc[14]=q3.z; wc[15]=q3.w;

    unsigned rm[ML];
    #pragma unroll
    for (int t = 0; t < ML; ++t) rm[t] = cm[wc[t]];

    const int wl = word_lengths[w];
    const float maxdist = (float)(seq_wl + wl) * s;
    const float mdp1 = maxdist + 1.0f;
    const int rowcap = wl + 1;        // per-lane capture row (17 -> never -> 0)

    float prev[ML], tb[15], mk[ML];
    #pragma unroll
    for (int j = 0; j < ML; ++j) prev[j] = maxdist;
    #pragma unroll
    for (int t = 0; t < 15; ++t) tb[t] = maxdist;
    #pragma unroll
    for (int t = 0; t < ML; ++t) mk[t] = maxdist;

    float res = 0.0f;

    #pragma unroll
    for (int i = 1; i <= ML; ++i) {
        const int xi = xc[(i + 14) & 15];        // compile-time index now
        const float fi = (float)i;               // literal
        const float md_i = maxdist - fi;

        bool b[ML];
        #pragma unroll
        for (int t = 0; t < ML; ++t) b[t] = ((rm[t] >> i) & 1u) != 0u;
        #pragma unroll
        for (int t = 0; t < 15; ++t) if (b[t]) mk[t] = md_i;  // DA[i] level

        // up+1 of cell j is diag+1 of cell j+1: share one add per column
        float p1[ML];
        #pragma unroll
        for (int j = 0; j < ML; ++j) p1[j] = prev[j] + 1.0f;

        // ---- j = 1: char wc[15]; l = 0; k from DA[i-1] (mk[15] pre-update)
        const bool eq1 = (xi == wc[15]);
        const float trans1 = mk[15] + fi;              // maxdist + (i - k15)
        const float dce1 = eq1 ? maxdist : mdp1;       // diag(maxdist)+cost
        float cell = fminf(fminf(fminf(p1[0], mdp1), dce1), trans1);
        if (b[15]) mk[15] = md_i;                      // now DA[i] level
        bool pm = eq1;
        float left = cell;
        float cur[ML];
        cur[0] = cell;
        if (b[0]) tb[0] = cell - fi;                   // snap DP(i,1) for t=0
        if (su == 1) res = (i == rowcap) ? cell : res;

        #pragma unroll
        for (int j = 2; j <= ML; ++j) {
            const int t = j - 2;
            const bool eq = (xi == wc[t]);
            const float left1 = left + 1.0f;
            const float dce  = eq ? prev[j - 2] : p1[j - 2];   // diag + cost
            const float tln  = b[t] ? left : (tb[t] + fi);
            const float tl0  = mk[t] + (float)(i + j - 1);     // literal add
            const float trans = pm ? tln : tl0;
            const float cellv = fminf(fminf(fminf(p1[j - 1], left1), dce), trans);
            cur[j - 1] = cellv;
            if (j <= 15 && b[j - 1]) tb[j - 1] = cellv - fi;   // snap DP(i,j)
            if (su == j) res = (i == rowcap) ? cellv : res;
            pm = eq;
            left = cellv;
        }
        #pragma unroll
        for (int j = 0; j < ML; ++j) prev[j] = cur[j];
    }

    if (active) out[bs * NW + w] = res;
}

extern "C" void kernel_launch(void* const* d_in, const int* in_sizes, int n_in,
                              void* d_out, int out_size, void* d_ws, size_t ws_size,
                              hipStream_t stream) {
    const int*   x            = (const int*)d_in[0];
    const int*   words        = (const int*)d_in[1];
    const int*   word_lengths = (const int*)d_in[2];
    const float* out_scale    = (const float*)d_in[3];
    float*       out          = (float*)d_out;

    dl_fused_kernel<<<dim3(NBS * 4), dim3(256), 0, stream>>>(
        x, words, word_lengths, out_scale, out);
}

// Round 2
// 69.914 us; speedup vs baseline: 1.0251x; 1.0021x over previous
//
#include <hip/hip_runtime.h>

#define ML 16
#define NW 1000
#define NBS 64

// Fused kernel: each block rebuilds the global char->row bitmask from x
// (4 KB, L2-resident) in LDS, then runs the register-resident DP.
//
// charmask cm[c]: bit i (i=1..16) set iff any of the 64 sequences has char c
// at x-position (i-2) & 15  (row i uses x[:,:,i-2]; Python negative-index
// wrap: i=1 -> pos 15). The reference's DA table is GLOBAL across all
// (b,s) sequences, so a global charmask is semantically correct.
//
// Per-lane DP state (one lane per (b,s,word)):
//  - prev[16]: DP row, updated IN PLACE (diag/up rotation)
//  - mk[t]   : maxdist - k_t  (k_t = DA[i][wc[t]]; k=0 -> mk=maxdist)
//  - tb[t]   : DP(k, t+1) - k at last row k where wc[t] appeared
//              (k=0 -> tb=maxdist, folds the border case)
// Transposition term per cell (i,j), t=j-2:
//   l==0          -> trans = mk[t] + (i + j - 1)
//   l=j-1, k==i   -> trans = left   (previous cell in current row)
//   l=j-1, k<i    -> trans = tb[t] + i
//
// v3 changes vs v2 (70.06 us):
//  - __launch_bounds__(256, 1): grid is exactly 1 block/CU (256 blocks on
//    256 CUs -> 1 wave/SIMD), so ANY VGPR count <= 512 costs no occupancy.
//    Without the min-waves hint the allocator may target a smaller budget
//    and spill; at 1 wave/SIMD spills are fully latency-exposed.
//  - in-place DP row (diag/up rotation) kills cur[16] and p1[16]:
//    ~32 fewer live VGPRs. d1 (= diag+1) carries last cell's up+1, keeping
//    the shared-add trick without the p1[] array.
__global__ __launch_bounds__(256, 1) void dl_fused_kernel(
    const int* __restrict__ x,
    const int* __restrict__ words,
    const int* __restrict__ word_lengths,
    const float* __restrict__ out_scale,
    float* __restrict__ out)
{
    __shared__ unsigned cm[32];
    const int tid = threadIdx.x;
    const int lane = tid & 63;
    const int wv = tid >> 6;                     // 0..3
    const int bs = blockIdx.x >> 2;              // 0..63
    const int chunk = (blockIdx.x & 3) * 4 + wv; // 0..15
    const int w_raw = chunk * 64 + lane;
    const bool active = (w_raw < NW);
    const int w = active ? w_raw : (NW - 1);
    const float s = out_scale[0];

    // ---- build charmask in LDS (64 lanes cooperate; 64 seqs) ----
    if (tid < 32) cm[tid] = 0u;
    __syncthreads();
    if (tid < 64) {
        const int* xq = x + tid * ML;
        #pragma unroll
        for (int p = 0; p < ML; ++p) {
            int c = xq[p];                       // 0..27
            int i = (p <= 14) ? (p + 2) : 1;
            atomicOr(&cm[c], 1u << i);
        }
    }
    __syncthreads();

    // ---- block-uniform x row: argmin (first min) = seq_wl ----
    const int* xr = x + bs * ML;
    int xc[ML];
    #pragma unroll
    for (int p = 0; p < ML; ++p) xc[p] = xr[p];
    int minv = xc[0], seq_wl = 0;
    #pragma unroll
    for (int p = 1; p < ML; ++p)
        if (xc[p] < minv) { minv = xc[p]; seq_wl = p; }
    // block-uniform capture column (1..16) -> scalar register
    const int su = __builtin_amdgcn_readfirstlane(seq_wl + 1);

    // ---- per-lane word chars (coalesced 16B loads) + row bitmasks ----
    int wc[ML];
    const int4* wp = (const int4*)(words + w * ML);
    int4 q0 = wp[0], q1 = wp[1], q2 = wp[2], q3 = wp[3];
    wc[0]=q0.x; wc[1]=q0.y; wc[2]=q0.z; wc[3]=q0.w;
    wc[4]=q1.x; wc[5]=q1.y; wc[6]=q1.z; wc[7]=q1.w;
    wc[8]=q2.x; wc[9]=q2.y; wc[10]=q2.z; wc[11]=q2.w;
    wc[12]=q3.x; wc[13]=q3.y; wc[14]=q3.z; wc[15]=q3.w;

    unsigned rm[ML];
    #pragma unroll
    for (int t = 0; t < ML; ++t) rm[t] = cm[wc[t]];

    const int wl = word_lengths[w];
    const float maxdist = (float)(seq_wl + wl) * s;
    const float mdp1 = maxdist + 1.0f;
    const int rowcap = wl + 1;        // per-lane capture row (17 -> never -> 0)

    float prev[ML], tb[15], mk[ML];
    #pragma unroll
    for (int j = 0; j < ML; ++j) prev[j] = maxdist;
    #pragma unroll
    for (int t = 0; t < 15; ++t) tb[t] = maxdist;
    #pragma unroll
    for (int t = 0; t < ML; ++t) mk[t] = maxdist;

    float res = 0.0f;

    #pragma unroll
    for (int i = 1; i <= ML; ++i) {
        const int xi = xc[(i + 14) & 15];        // compile-time index
        const float fi = (float)i;               // literal
        const float md_i = maxdist - fi;

        bool b[ML];
        #pragma unroll
        for (int t = 0; t < ML; ++t) b[t] = ((rm[t] >> i) & 1u) != 0u;
        #pragma unroll
        for (int t = 0; t < 15; ++t) if (b[t]) mk[t] = md_i;  // DA[i] level

        // ---- j = 1: char wc[15]; l = 0; k from DA[i-1] (mk[15] pre-update)
        // borders: diag = d[i-1][0] = maxdist, left = d[i][0] = maxdist
        const bool eq1 = (xi == wc[15]);
        const float trans1 = mk[15] + fi;              // maxdist + (i - k15)
        const float up1f = prev[0];
        const float u11 = up1f + 1.0f;
        const float dce1 = eq1 ? maxdist : mdp1;       // diag + cost
        float cell = fminf(fminf(fminf(u11, mdp1), dce1), trans1);
        if (b[15]) mk[15] = md_i;                      // now DA[i] level
        bool pm = eq1;
        float left = cell;
        float diag = up1f;                             // old prev[0]
        float d1 = u11;                                // diag + 1
        prev[0] = cell;
        if (b[0]) tb[0] = cell - fi;                   // snap DP(i,1) for t=0
        if (su == 1) res = (i == rowcap) ? cell : res;

        #pragma unroll
        for (int j = 2; j <= ML; ++j) {
            const int t = j - 2;
            const bool eq = (xi == wc[t]);
            const float up = prev[j - 1];              // old row, column j
            const float u1 = up + 1.0f;
            const float left1 = left + 1.0f;
            const float dce  = eq ? diag : d1;         // diag + cost
            const float tln  = b[t] ? left : (tb[t] + fi);
            const float tl0  = mk[t] + (float)(i + j - 1);  // literal add
            const float trans = pm ? tln : tl0;
            const float cellv = fminf(fminf(fminf(u1, left1), dce), trans);
            prev[j - 1] = cellv;                       // in-place: new row
            if (j <= 15 && b[j - 1]) tb[j - 1] = cellv - fi; // snap DP(i,j)
            if (su == j) res = (i == rowcap) ? cellv : res;
            pm = eq;
            left = cellv;
            diag = up;
            d1 = u1;
        }
    }

    if (active) out[bs * NW + w] = res;
}

extern "C" void kernel_launch(void* const* d_in, const int* in_sizes, int n_in,
                              void* d_out, int out_size, void* d_ws, size_t ws_size,
                              hipStream_t stream) {
    const int*   x            = (const int*)d_in[0];
    const int*   words        = (const int*)d_in[1];
    const int*   word_lengths = (const int*)d_in[2];
    const float* out_scale    = (const float*)d_in[3];
    float*       out          = (float*)d_out;

    dl_fused_kernel<<<dim3(NBS * 4), dim3(256), 0, stream>>>(
        x, words, word_lengths, out_scale, out);
}